// Round 9
// baseline (100.624 us; speedup 1.0000x reference)
//
#include <hip/hip_runtime.h>
#include <cmath>

// Problem geometry (fixed: im is (1, 4096, 4096, 3) f32 NHWC)
constexpr int H   = 4096;
constexpr int W   = 4096;
constexpr int C   = 3;
constexpr int WF  = W * C;       // 12288 floats per image row
constexpr int EPT = 8;           // floats per thread (contiguous)
constexpr int TW  = 256 * EPT;   // 2048 floats per block
constexpr int RPT = 16;          // output rows per block

// sqrt(v + 0.375); the Anscombe 2x is folded into the horizontal weights.
__device__ __forceinline__ float sq1(float v) {
    return __builtin_amdgcn_sqrtf(v + 0.375f);
}
__device__ __forceinline__ float4 sq4(float4 v) {
    return make_float4(sq1(v.x), sq1(v.y), sq1(v.z), sq1(v.w));
}

// Fused Anscombe -> separable 3x3 Gaussian (zero pad) -> clip -> inverse
// Anscombe. EPT=8 contiguous ownership: halo loads amortize over 8 outputs
// (4 loads + 16 sqrt per 8 outputs vs 6 + 24 for EPT=4). REGULAR stores:
// R5's +12% WRITE_SIZE was NT-evict of half-filled 64B sectors on the
// 16B-every-32B interleaved wave pattern; the adjacent-instruction pair
// completes each sector fine without NT (R2/R7 wrote exact 196608 KB).
// No LDS, no barriers, no cross-lane ops. Vertical 3-tap = rolling register
// window; compiler software-pipelines the fully-unrolled stage loop (R8
// showed explicit depth-2 prefetch is a no-op).
// R6 lesson: never force min-waves above live-state needs (spill disaster).
__global__ __launch_bounds__(256, 4) void anscombe_gauss_kernel(
    const float* __restrict__ in, float* __restrict__ out,
    float wa2, float wb2, float wa, float wb, float c1, float c3)
{
    const int tid = threadIdx.x;
    const int gc  = blockIdx.x * TW + tid * EPT;
    const int h0  = blockIdx.y * RPT;

    // Row-edge halo float4s (2 lanes in the whole grid): clamp + fill.
    const bool okL = (gc >= 4);
    const bool okR = (gc + 12 <= WF);
    const int offL = okL ? gc - 4 : gc;
    const int offR = okR ? gc + 8 : gc;

    const float4 cfill = make_float4(-0.375f, -0.375f, -0.375f, -0.375f);

    auto loadrow = [&](int h, float4& lo, float4& hi, float4& hl, float4& hr) {
        if ((unsigned)h < (unsigned)H) {
            const float* rp = in + (long)h * WF;
            lo = *(const float4*)(rp + gc);
            hi = *(const float4*)(rp + gc + 4);
            hl = *(const float4*)(rp + offL);
            hr = *(const float4*)(rp + offR);
            if (!okL) hl = cfill;
            if (!okR) hr = cfill;
        } else {
            lo = hi = hl = hr = cfill;   // OOB row: sqrt(0) == 0 == zero pad
        }
    };

    float4 nlo, nhi, nhl, nhr;
    loadrow(h0 - 1, nlo, nhi, nhl, nhr);

    float hp[8] = {0,0,0,0,0,0,0,0};
    float hc[8] = {0,0,0,0,0,0,0,0};

    #pragma unroll
    for (int s = 0; s < RPT + 2; ++s) {
        const float4 vlo = nlo, vhi = nhi, vhl = nhl, vhr = nhr;
        if (s < RPT + 1) loadrow(h0 + s, nlo, nhi, nhl, nhr);

        const float4 alo = sq4(vlo), ahi = sq4(vhi);
        const float m3 = sq1(vhl.y), m2 = sq1(vhl.z), m1 = sq1(vhl.w);
        const float p8 = sq1(vhr.x), p9 = sq1(vhr.y), pA = sq1(vhr.z);

        const float e0 = alo.x, e1 = alo.y, e2 = alo.z, e3 = alo.w;
        const float e4 = ahi.x, e5 = ahi.y, e6 = ahi.z, e7 = ahi.w;

        float hn[8];
        hn[0] = wa2 * (m3 + e3) + wb2 * e0;
        hn[1] = wa2 * (m2 + e4) + wb2 * e1;
        hn[2] = wa2 * (m1 + e5) + wb2 * e2;
        hn[3] = wa2 * (e0 + e6) + wb2 * e3;
        hn[4] = wa2 * (e1 + e7) + wb2 * e4;
        hn[5] = wa2 * (e2 + p8) + wb2 * e5;
        hn[6] = wa2 * (e3 + p9) + wb2 * e6;
        hn[7] = wa2 * (e4 + pA) + wb2 * e7;

        if (s >= 2) {
            const int ho = h0 + s - 2;
            float o[8];
            #pragma unroll
            for (int j = 0; j < 8; ++j) {
                float y = wa * (hp[j] + hn[j]) + wb * hc[j];
                y = __builtin_amdgcn_fmed3f(y, 0.0f, 255.0f);  // 1-op clamp
                // y >= ~0.17 always (center tap always in-image): rcp safe
                float ry = __builtin_amdgcn_rcpf(y);
                o[j] = fmaf(0.25f * y, y,
                        fmaf(ry, fmaf(ry, fmaf(ry, c3, -1.375f), c1), -0.125f));
            }
            float* op = out + (long)ho * WF + gc;
            *(float4*)(op)     = make_float4(o[0], o[1], o[2], o[3]);
            *(float4*)(op + 4) = make_float4(o[4], o[5], o[6], o[7]);
        }
        #pragma unroll
        for (int j = 0; j < 8; ++j) { hp[j] = hc[j]; hc[j] = hn[j]; }
    }
}

extern "C" void kernel_launch(void* const* d_in, const int* in_sizes, int n_in,
                              void* d_out, int out_size, void* d_ws, size_t ws_size,
                              hipStream_t stream) {
    const float* in = (const float*)d_in[0];
    float* out      = (float*)d_out;

    // Separable Gaussian weights (double precision on host).
    // 2D normalized kernel == outer([a,b,a],[a,b,a]) with a+b+a == 1.
    const double sig2x2 = 2.0 * 1.3 * 1.3;
    const double e1     = std::exp(-1.0 / sig2x2);
    const double inv1d  = 1.0 / (1.0 + 2.0 * e1);
    const float  wa     = (float)(e1 * inv1d);
    const float  wb     = (float)inv1d;
    const float  wa2    = (float)(2.0 * e1 * inv1d);   // Anscombe 2x folded in
    const float  wb2    = (float)(2.0 * inv1d);

    const double s  = std::sqrt(1.5);
    const float  c1 = (float)(0.25  * s);
    const float  c3 = (float)(0.625 * s);

    dim3 grid(WF / TW, H / RPT);   // 6 x 256 = 1536 blocks (6 per CU exactly)
    anscombe_gauss_kernel<<<grid, 256, 0, stream>>>(in, out, wa2, wb2, wa, wb, c1, c3);
}

// Round 10
// 73.240 us; speedup vs baseline: 1.3739x; 1.3739x over previous
//
#include <hip/hip_runtime.h>
#include <cmath>

// Problem geometry (fixed: im is (1, 4096, 4096, 3) f32 NHWC)
constexpr int H   = 4096;
constexpr int W   = 4096;
constexpr int C   = 3;
constexpr int WF  = W * C;     // 12288 floats per image row
constexpr int TW  = 1024;      // floats per block = 256 threads * 4
constexpr int RPT = 8;         // output rows per block (small strip -> max TLP)

typedef float f32x4 __attribute__((ext_vector_type(4)));  // nt-store friendly

// sqrt(v + 0.375); the Anscombe 2x is folded into the horizontal weights.
__device__ __forceinline__ float sq1(float v) {
    return __builtin_amdgcn_sqrtf(v + 0.375f);
}
__device__ __forceinline__ float4 sq4(float4 v) {
    return make_float4(sq1(v.x), sq1(v.y), sq1(v.z), sq1(v.w));
}

// Fused Anscombe -> separable 3x3 Gaussian (zero pad) -> clip -> inverse
// Anscombe. One float4 per thread per row: every wave-wide load AND store
// instruction spans a contiguous 1KB block (sector-complete stores -> NT
// streams with zero amplification; R9 showed EPT=8 interleaved + regular
// stores RMWs partial sectors, +14us). NT stores bypass L2 -> reads keep the
// cache (R5's win). RPT=8 strips, 6144 blocks: 24 waves/CU demanded, VGPR
// ~40 -> residency capped only by HW 8 waves/SIMD -> near-full occupancy to
// cover read latency by TLP (the ~85us wall had occ <= 68%).
// R6 lesson: never force min-waves above live-state needs (spill disaster).
__global__ __launch_bounds__(256, 4) void anscombe_gauss_kernel(
    const float* __restrict__ in, float* __restrict__ out,
    float wa2, float wb2, float wa, float wb, float c1, float c3)
{
    const int tid = threadIdx.x;
    const int gc  = blockIdx.x * TW + tid * 4;   // this thread's float4 column
    const int h0  = blockIdx.y * RPT;

    // Row-edge lanes (2 in the whole grid): clamp address, fill after load.
    const bool okL = (gc >= 4);
    const bool okR = (gc + 8 <= WF);
    const int offL = okL ? gc - 4 : gc;
    const int offR = okR ? gc + 4 : gc;

    const float4 cfill = make_float4(-0.375f, -0.375f, -0.375f, -0.375f);

    auto loadrow = [&](int h, float4& c, float4& l, float4& r) {
        if ((unsigned)h < (unsigned)H) {
            const float* rp = in + (long)h * WF;
            c = *(const float4*)(rp + gc);
            l = *(const float4*)(rp + offL);
            r = *(const float4*)(rp + offR);
            if (!okL) l = cfill;
            if (!okR) r = cfill;
        } else {
            c = l = r = cfill;           // OOB row: sqrt(0) == 0 == zero pad
        }
    };

    float4 pc, pl, pr;
    loadrow(h0 - 1, pc, pl, pr);

    float hp[4] = {0, 0, 0, 0};
    float hc[4] = {0, 0, 0, 0};

    #pragma unroll
    for (int s = 0; s < RPT + 2; ++s) {
        const float4 vc = pc, vl = pl, vr = pr;
        if (s < RPT + 1) loadrow(h0 + s, pc, pl, pr);   // prefetch next row

        const float4 a  = sq4(vc);
        const float4 aL = sq4(vl);
        const float4 aR = sq4(vr);

        float hn[4];
        hn[0] = wa2 * (aL.y + a.w)  + wb2 * a.x;
        hn[1] = wa2 * (aL.z + aR.x) + wb2 * a.y;
        hn[2] = wa2 * (aL.w + aR.y) + wb2 * a.z;
        hn[3] = wa2 * (a.x  + aR.z) + wb2 * a.w;

        if (s >= 2) {
            const int ho = h0 + s - 2;
            float o[4];
            #pragma unroll
            for (int j = 0; j < 4; ++j) {
                float y = wa * (hp[j] + hn[j]) + wb * hc[j];
                y = __builtin_amdgcn_fmed3f(y, 0.0f, 255.0f);  // 1-op clamp
                // y >= ~0.17 always (center tap always in-image): rcp safe
                float ry = __builtin_amdgcn_rcpf(y);
                o[j] = fmaf(0.25f * y, y,
                        fmaf(ry, fmaf(ry, fmaf(ry, c3, -1.375f), c1), -0.125f));
            }
            f32x4 ov = {o[0], o[1], o[2], o[3]};
            __builtin_nontemporal_store(ov, (f32x4*)(out + (long)ho * WF + gc));
        }
        #pragma unroll
        for (int j = 0; j < 4; ++j) { hp[j] = hc[j]; hc[j] = hn[j]; }
    }
}

extern "C" void kernel_launch(void* const* d_in, const int* in_sizes, int n_in,
                              void* d_out, int out_size, void* d_ws, size_t ws_size,
                              hipStream_t stream) {
    const float* in = (const float*)d_in[0];
    float* out      = (float*)d_out;

    // Separable Gaussian weights (double precision on host).
    // 2D normalized kernel == outer([a,b,a],[a,b,a]) with a+b+a == 1.
    const double sig2x2 = 2.0 * 1.3 * 1.3;
    const double e1     = std::exp(-1.0 / sig2x2);
    const double inv1d  = 1.0 / (1.0 + 2.0 * e1);
    const float  wa     = (float)(e1 * inv1d);
    const float  wb     = (float)inv1d;
    const float  wa2    = (float)(2.0 * e1 * inv1d);   // Anscombe 2x folded in
    const float  wb2    = (float)(2.0 * inv1d);

    const double s  = std::sqrt(1.5);
    const float  c1 = (float)(0.25  * s);
    const float  c3 = (float)(0.625 * s);

    dim3 grid(WF / TW, H / RPT);   // 12 x 512 = 6144 blocks (24 waves/CU demand)
    anscombe_gauss_kernel<<<grid, 256, 0, stream>>>(in, out, wa2, wb2, wa, wb, c1, c3);
}